// Round 2
// baseline (987.815 us; speedup 1.0000x reference)
//
#include <hip/hip_runtime.h>

// GCN: x[N,128] -> GCNConv(W1,b1)+relu -> MLP(64->128->64, relu,relu) -> GCNConv(W2,b2)
// Aggregation: out[d] = sum_e dis[src]*dis[dst]*m[src] (+ self loop) + bias
//
// Workspace layout (floats):
//   deg  : [0, N)
//   dis  : [N, 2N)
//   hs1  : [2N, 2N+64N)      pre-scaled layer-1 messages (x@W1)*dis[n]
//   agg1 : [2N+64N, 2N+128N) layer-1 aggregation buffer (init = self-loop + b1)
//   ms2  : [2N+128N, 2N+160N) pre-scaled layer-2 messages (h3@W2)*dis[n]
// Total = 162*N floats = 64.8 MB

static constexpr int TPB = 256;

__device__ __forceinline__ float rdlane(float v, int l) {
  return __builtin_bit_cast(float, __builtin_amdgcn_readlane(__builtin_bit_cast(int, v), l));
}

__global__ __launch_bounds__(TPB) void k_deg_init(float* __restrict__ deg, int n) {
  int i = blockIdx.x * TPB + threadIdx.x;
  if (i < n) deg[i] = 1.0f;  // self-loop
}

__global__ __launch_bounds__(TPB) void k_deg_edges(const int* __restrict__ dst,
                                                   float* __restrict__ deg, int e) {
  int i = blockIdx.x * TPB + threadIdx.x;
  if (i < e) atomicAdd(&deg[dst[i]], 1.0f);
}

__global__ __launch_bounds__(TPB) void k_dis(const float* __restrict__ deg,
                                             float* __restrict__ dis, int n) {
  int i = blockIdx.x * TPB + threadIdx.x;
  if (i < n) dis[i] = rsqrtf(deg[i]);
}

// h1 = x @ W1 (128->64); hs1 = h1*dis[n]; agg1 init = h1*dis^2 + b1
__global__ __launch_bounds__(TPB) void k_lin1(
    const float* __restrict__ x, const float* __restrict__ W1,
    const float* __restrict__ b1, const float* __restrict__ dis,
    float* __restrict__ hs1, float* __restrict__ agg1, int n) {
  __shared__ float sW[128 * 64];
  __shared__ float sb[64];
  for (int i = threadIdx.x; i < 128 * 64; i += TPB) sW[i] = W1[i];
  if (threadIdx.x < 64) sb[threadIdx.x] = b1[threadIdx.x];
  __syncthreads();

  const int w = threadIdx.x >> 6, lane = threadIdx.x & 63;
  const int wid = blockIdx.x * 4 + w;
  const int nw = gridDim.x * 4;
  for (int node = wid; node < n; node += nw) {
    float xv0 = x[node * 128 + lane];
    float xv1 = x[node * 128 + 64 + lane];
    float acc0 = 0.f, acc1 = 0.f;  // two chains to hide FMA latency
#pragma unroll
    for (int k = 0; k < 64; ++k) {
      acc0 = fmaf(rdlane(xv0, k), sW[k * 64 + lane], acc0);
      acc1 = fmaf(rdlane(xv1, k), sW[(k + 64) * 64 + lane], acc1);
    }
    float d = dis[node];
    float v = (acc0 + acc1) * d;
    hs1[node * 64 + lane] = v;
    agg1[node * 64 + lane] = fmaf(v, d, sb[lane]);
  }
}

// agg1[dst] += hs1[src] * dis[dst]   (one wave per edge, 64 features)
__global__ __launch_bounds__(TPB) void k_edge1(
    const int* __restrict__ src, const int* __restrict__ dst,
    const float* __restrict__ dis, const float* __restrict__ hs1,
    float* __restrict__ agg1, int e) {
  int t = blockIdx.x * TPB + threadIdx.x;
  int edge = t >> 6;
  int j = t & 63;
  if (edge >= e) return;
  int s = src[edge], d = dst[edge];
  float val = hs1[s * 64 + j] * dis[d];
  atomicAdd(&agg1[d * 64 + j], val);
}

// h = relu(agg1); t1 = relu(h@Wl1+bl1); t2 = relu(t1@Wl2+bl2); m2 = t2@W2
// ms2 = m2*dis; out init = m2*dis^2 + b2
__global__ __launch_bounds__(TPB) void k_mlp(
    const float* __restrict__ agg1,
    const float* __restrict__ Wl1, const float* __restrict__ bl1,
    const float* __restrict__ Wl2, const float* __restrict__ bl2,
    const float* __restrict__ W2, const float* __restrict__ b2,
    const float* __restrict__ dis,
    float* __restrict__ ms2, float* __restrict__ out, int n) {
  __shared__ float sW1[64 * 128];
  __shared__ float sW2[128 * 64];
  __shared__ float sW3[64 * 32];
  __shared__ float sb1[128], sb2[64], sb3[32];
  for (int i = threadIdx.x; i < 64 * 128; i += TPB) sW1[i] = Wl1[i];
  for (int i = threadIdx.x; i < 128 * 64; i += TPB) sW2[i] = Wl2[i];
  for (int i = threadIdx.x; i < 64 * 32; i += TPB) sW3[i] = W2[i];
  if (threadIdx.x < 128) sb1[threadIdx.x] = bl1[threadIdx.x];
  if (threadIdx.x < 64) sb2[threadIdx.x] = bl2[threadIdx.x];
  if (threadIdx.x < 32) sb3[threadIdx.x] = b2[threadIdx.x];
  __syncthreads();

  const int w = threadIdx.x >> 6, lane = threadIdx.x & 63;
  const int wid = blockIdx.x * 4 + w;
  const int nw = gridDim.x * 4;
  for (int node = wid; node < n; node += nw) {
    float h = fmaxf(agg1[node * 64 + lane], 0.f);
    // t1: columns lane and lane+64
    float t1a = sb1[lane], t1b = sb1[lane + 64];
#pragma unroll
    for (int k = 0; k < 64; ++k) {
      float hk = rdlane(h, k);
      t1a = fmaf(hk, sW1[k * 128 + lane], t1a);
      t1b = fmaf(hk, sW1[k * 128 + 64 + lane], t1b);
    }
    t1a = fmaxf(t1a, 0.f);
    t1b = fmaxf(t1b, 0.f);
    // t2: column lane
    float t2 = sb2[lane];
#pragma unroll
    for (int k = 0; k < 64; ++k) {
      t2 = fmaf(rdlane(t1a, k), sW2[k * 64 + lane], t2);
      t2 = fmaf(rdlane(t1b, k), sW2[(k + 64) * 64 + lane], t2);
    }
    t2 = fmaxf(t2, 0.f);
    // m2: 32 columns; all lanes compute (lanes>=32 duplicate), lanes<32 store
    int col = lane & 31;
    float m0 = 0.f, m1 = 0.f;
#pragma unroll
    for (int k = 0; k < 64; k += 2) {
      m0 = fmaf(rdlane(t2, k), sW3[k * 32 + col], m0);
      m1 = fmaf(rdlane(t2, k + 1), sW3[(k + 1) * 32 + col], m1);
    }
    float m = m0 + m1;
    float d = dis[node];
    float md = m * d;
    if (lane < 32) {
      ms2[node * 32 + col] = md;
      out[node * 32 + col] = fmaf(md, d, sb3[col]);
    }
  }
}

// out[dst] += ms2[src] * dis[dst]   (half-wave per edge, 32 features)
__global__ __launch_bounds__(TPB) void k_edge2(
    const int* __restrict__ src, const int* __restrict__ dst,
    const float* __restrict__ dis, const float* __restrict__ ms2,
    float* __restrict__ out, int e) {
  int t = blockIdx.x * TPB + threadIdx.x;
  int edge = t >> 5;
  int j = t & 31;
  if (edge >= e) return;
  int s = src[edge], d = dst[edge];
  float val = ms2[s * 32 + j] * dis[d];
  atomicAdd(&out[d * 32 + j], val);
}

extern "C" void kernel_launch(void* const* d_in, const int* in_sizes, int n_in,
                              void* d_out, int out_size, void* d_ws, size_t ws_size,
                              hipStream_t stream) {
  const float* x   = (const float*)d_in[0];
  const int* ei    = (const int*)d_in[1];
  const float* W1  = (const float*)d_in[2];
  const float* b1  = (const float*)d_in[3];
  const float* Wl1 = (const float*)d_in[4];
  const float* bl1 = (const float*)d_in[5];
  const float* Wl2 = (const float*)d_in[6];
  const float* bl2 = (const float*)d_in[7];
  const float* W2  = (const float*)d_in[8];
  const float* b2  = (const float*)d_in[9];
  float* out = (float*)d_out;

  const int n = in_sizes[0] / 128;
  const int e = in_sizes[1] / 2;
  const int* src = ei;
  const int* dst = ei + e;

  float* ws   = (float*)d_ws;
  float* deg  = ws;
  float* dis  = ws + n;
  float* hs1  = ws + 2 * n;
  float* agg1 = ws + 2 * n + 64 * n;
  float* ms2  = ws + 2 * n + 128 * n;

  const int gN = (n + TPB - 1) / TPB;
  const int gE = (e + TPB - 1) / TPB;

  k_deg_init<<<gN, TPB, 0, stream>>>(deg, n);
  k_deg_edges<<<gE, TPB, 0, stream>>>(dst, deg, e);
  k_dis<<<gN, TPB, 0, stream>>>(deg, dis, n);
  k_lin1<<<1024, TPB, 0, stream>>>(x, W1, b1, dis, hs1, agg1, n);
  {
    long long tot = (long long)e * 64;
    int grid = (int)((tot + TPB - 1) / TPB);
    k_edge1<<<grid, TPB, 0, stream>>>(src, dst, dis, hs1, agg1, e);
  }
  k_mlp<<<512, TPB, 0, stream>>>(agg1, Wl1, bl1, Wl2, bl2, W2, b2, dis, ms2, out, n);
  {
    long long tot = (long long)e * 32;
    int grid = (int)((tot + TPB - 1) / TPB);
    k_edge2<<<grid, TPB, 0, stream>>>(src, dst, dis, ms2, out, e);
  }
}

// Round 3
// 765.502 us; speedup vs baseline: 1.2904x; 1.2904x over previous
//
#include <hip/hip_runtime.h>

// GCN via device-built CSR (dst-indexed), gather aggregation — no float atomics.
//
// out[d] = dis[d] * ( sum_{e: dst=d} hs[src] + hs[d] ) + bias,  hs = (h@W)*dis[src]
//
// Workspace layout (4-byte words):
//   dis      [0, n)
//   cnt      [n, 2n)          in-degree (excl self-loop), int
//   rowstart [2n, 3n+4)       exclusive scan, int (n+1 used)
//   cursor   [3n+4, 4n+4)     fill cursors, int
//   bsums    [4n+4, 4n+1028)  scan block sums, int
//   csr      [4n+1028, +e)    src indices grouped by dst
//   hs1      [.., +64n)       layer-1 messages (x@W1)*dis   (reused as ms2 later)
//   agg1     [.., +64n)       aggregated layer-1 activations
// Total = 132n + e + 1028 words ≈ 59.3 MB

static constexpr int TPB = 256;

__device__ __forceinline__ float rdlanef(float v, int l) {
  return __builtin_bit_cast(float, __builtin_amdgcn_readlane(__builtin_bit_cast(int, v), l));
}

// ---------- degree / normalization ----------
__global__ __launch_bounds__(TPB) void k_cnt_init(int* __restrict__ cnt, int n) {
  int i = blockIdx.x * TPB + threadIdx.x;
  if (i < n) cnt[i] = 0;
}

__global__ __launch_bounds__(TPB) void k_cnt(const int* __restrict__ dst,
                                             int* __restrict__ cnt, int e) {
  int i = blockIdx.x * TPB + threadIdx.x;
  if (i < e) atomicAdd(&cnt[dst[i]], 1);
}

__global__ __launch_bounds__(TPB) void k_dis(const int* __restrict__ cnt,
                                             float* __restrict__ dis, int n) {
  int i = blockIdx.x * TPB + threadIdx.x;
  if (i < n) dis[i] = rsqrtf((float)(cnt[i] + 1));  // +1 = self-loop
}

// ---------- exclusive scan (1024 elems/block) ----------
__global__ __launch_bounds__(TPB) void k_scanA(const int* __restrict__ cnt,
                                               int* __restrict__ bsums, int n) {
  int base = blockIdx.x * 1024 + threadIdx.x * 4;
  int s = 0;
#pragma unroll
  for (int q = 0; q < 4; ++q) if (base + q < n) s += cnt[base + q];
  int lane = threadIdx.x & 63, wv = threadIdx.x >> 6;
#pragma unroll
  for (int off = 32; off; off >>= 1) s += __shfl_down(s, off);
  __shared__ int ls[4];
  if (lane == 0) ls[wv] = s;
  __syncthreads();
  if (threadIdx.x == 0) bsums[blockIdx.x] = ls[0] + ls[1] + ls[2] + ls[3];
}

__global__ void k_scanB(int* __restrict__ bsums, int nb,
                        int* __restrict__ rowstart, int n) {
  int acc = 0;
  for (int i = 0; i < nb; ++i) { int v = bsums[i]; bsums[i] = acc; acc += v; }
  rowstart[n] = acc;
}

__global__ __launch_bounds__(TPB) void k_scanC(const int* __restrict__ cnt,
                                               const int* __restrict__ bsums,
                                               int* __restrict__ rowstart,
                                               int* __restrict__ cursor, int n) {
  int base = blockIdx.x * 1024 + threadIdx.x * 4;
  int v[4] = {0, 0, 0, 0};
#pragma unroll
  for (int q = 0; q < 4; ++q) if (base + q < n) v[q] = cnt[base + q];
  int mysum = v[0] + v[1] + v[2] + v[3];
  int s = mysum;
  int lane = threadIdx.x & 63, wv = threadIdx.x >> 6;
#pragma unroll
  for (int off = 1; off < 64; off <<= 1) {
    int t = __shfl_up(s, off);
    if (lane >= off) s += t;
  }
  __shared__ int ls[4];
  if (lane == 63) ls[wv] = s;
  __syncthreads();
  int woff = 0;
  for (int w2 = 0; w2 < wv; ++w2) woff += ls[w2];
  int ex = bsums[blockIdx.x] + woff + (s - mysum);
#pragma unroll
  for (int q = 0; q < 4; ++q) {
    if (base + q < n) { rowstart[base + q] = ex; cursor[base + q] = 0; }
    ex += v[q];
  }
}

__global__ __launch_bounds__(TPB) void k_fill(const int* __restrict__ src,
                                              const int* __restrict__ dst,
                                              const int* __restrict__ rowstart,
                                              int* __restrict__ cursor,
                                              int* __restrict__ csr, int e) {
  int i = blockIdx.x * TPB + threadIdx.x;
  if (i >= e) return;
  int d = dst[i];
  int pos = rowstart[d] + atomicAdd(&cursor[d], 1);
  csr[pos] = src[i];
}

// ---------- layer 1 linear: hs1 = (x @ W1) * dis ----------
__global__ __launch_bounds__(TPB) void k_lin1(
    const float* __restrict__ x, const float* __restrict__ W1,
    const float* __restrict__ dis, float* __restrict__ hs1, int n) {
  __shared__ float sW[128 * 64];
  for (int i = threadIdx.x; i < 128 * 64; i += TPB) sW[i] = W1[i];
  __syncthreads();
  const int w = threadIdx.x >> 6, lane = threadIdx.x & 63;
  const int wid = blockIdx.x * 4 + w;
  const int nw = gridDim.x * 4;
  for (int node = wid; node < n; node += nw) {
    float xv0 = x[node * 128 + lane];
    float xv1 = x[node * 128 + 64 + lane];
    float acc0 = 0.f, acc1 = 0.f;
#pragma unroll
    for (int k = 0; k < 64; ++k) {
      acc0 = fmaf(rdlanef(xv0, k), sW[k * 64 + lane], acc0);
      acc1 = fmaf(rdlanef(xv1, k), sW[(k + 64) * 64 + lane], acc1);
    }
    hs1[node * 64 + lane] = (acc0 + acc1) * dis[node];
  }
}

// ---------- layer-1 aggregation: one wave per node, 64 feats ----------
__global__ __launch_bounds__(TPB) void k_agg1(
    const int* __restrict__ rowstart, const int* __restrict__ csr,
    const float* __restrict__ hs1, const float* __restrict__ dis,
    const float* __restrict__ b1, float* __restrict__ agg1, int n) {
  int node = (blockIdx.x * TPB + threadIdx.x) >> 6;
  int lane = threadIdx.x & 63;
  if (node >= n) return;
  int beg = rowstart[node], end = rowstart[node + 1];
  float acc = hs1[node * 64 + lane];  // self-loop term
  for (int base = beg; base < end; base += 64) {
    int cntc = min(64, end - base);
    int sidx = (base + lane < end) ? csr[base + lane] : 0;
    for (int k = 0; k < cntc; ++k) {
      int s = __builtin_amdgcn_readlane(sidx, k);
      acc += hs1[s * 64 + lane];
    }
  }
  agg1[node * 64 + lane] = fmaf(acc, dis[node], b1[lane]);
}

// ---------- MLP + layer-2 linear: ms2 = (relu-MLP(relu(agg1)) @ W2) * dis ----------
__global__ __launch_bounds__(TPB) void k_mlp(
    const float* __restrict__ agg1,
    const float* __restrict__ Wl1, const float* __restrict__ bl1,
    const float* __restrict__ Wl2, const float* __restrict__ bl2,
    const float* __restrict__ W2, const float* __restrict__ dis,
    float* __restrict__ ms2, int n) {
  __shared__ float sW1[64 * 128];
  __shared__ float sW2[128 * 64];
  __shared__ float sW3[64 * 32];
  __shared__ float sb1[128], sb2[64];
  for (int i = threadIdx.x; i < 64 * 128; i += TPB) sW1[i] = Wl1[i];
  for (int i = threadIdx.x; i < 128 * 64; i += TPB) sW2[i] = Wl2[i];
  for (int i = threadIdx.x; i < 64 * 32; i += TPB) sW3[i] = W2[i];
  if (threadIdx.x < 128) sb1[threadIdx.x] = bl1[threadIdx.x];
  if (threadIdx.x < 64) sb2[threadIdx.x] = bl2[threadIdx.x];
  __syncthreads();

  const int w = threadIdx.x >> 6, lane = threadIdx.x & 63;
  const int wid = blockIdx.x * 4 + w;
  const int nw = gridDim.x * 4;
  for (int node = wid; node < n; node += nw) {
    float h = fmaxf(agg1[node * 64 + lane], 0.f);
    float t1a = sb1[lane], t1b = sb1[lane + 64];
#pragma unroll
    for (int k = 0; k < 64; ++k) {
      float hk = rdlanef(h, k);
      t1a = fmaf(hk, sW1[k * 128 + lane], t1a);
      t1b = fmaf(hk, sW1[k * 128 + 64 + lane], t1b);
    }
    t1a = fmaxf(t1a, 0.f);
    t1b = fmaxf(t1b, 0.f);
    float t2 = sb2[lane];
#pragma unroll
    for (int k = 0; k < 64; ++k) {
      t2 = fmaf(rdlanef(t1a, k), sW2[k * 64 + lane], t2);
      t2 = fmaf(rdlanef(t1b, k), sW2[(k + 64) * 64 + lane], t2);
    }
    t2 = fmaxf(t2, 0.f);
    int col = lane & 31;
    float m0 = 0.f, m1 = 0.f;
#pragma unroll
    for (int k = 0; k < 64; k += 2) {
      m0 = fmaf(rdlanef(t2, k), sW3[k * 32 + col], m0);
      m1 = fmaf(rdlanef(t2, k + 1), sW3[(k + 1) * 32 + col], m1);
    }
    if (lane < 32) ms2[node * 32 + col] = (m0 + m1) * dis[node];
  }
}

// ---------- layer-2 aggregation: half-wave per node, 32 feats ----------
__global__ __launch_bounds__(TPB) void k_agg2(
    const int* __restrict__ rowstart, const int* __restrict__ csr,
    const float* __restrict__ ms2, const float* __restrict__ dis,
    const float* __restrict__ b2, float* __restrict__ out, int n) {
  int t = blockIdx.x * TPB + threadIdx.x;
  int node = t >> 5;
  int j = t & 31;
  if (node >= n) return;
  int beg = rowstart[node], end = rowstart[node + 1];
  float acc = ms2[node * 32 + j];  // self-loop term
  for (int k = beg; k < end; ++k) {
    int s = csr[k];
    acc += ms2[s * 32 + j];
  }
  out[node * 32 + j] = fmaf(acc, dis[node], b2[j]);
}

extern "C" void kernel_launch(void* const* d_in, const int* in_sizes, int n_in,
                              void* d_out, int out_size, void* d_ws, size_t ws_size,
                              hipStream_t stream) {
  const float* x   = (const float*)d_in[0];
  const int* ei    = (const int*)d_in[1];
  const float* W1  = (const float*)d_in[2];
  const float* b1  = (const float*)d_in[3];
  const float* Wl1 = (const float*)d_in[4];
  const float* bl1 = (const float*)d_in[5];
  const float* Wl2 = (const float*)d_in[6];
  const float* bl2 = (const float*)d_in[7];
  const float* W2  = (const float*)d_in[8];
  const float* b2  = (const float*)d_in[9];
  float* out = (float*)d_out;

  const int n = in_sizes[0] / 128;
  const int e = in_sizes[1] / 2;
  const int* src = ei;
  const int* dst = ei + e;

  int* wsw = (int*)d_ws;
  float* dis     = (float*)wsw;
  int* cnt       = wsw + n;
  int* rowstart  = wsw + 2 * n;
  int* cursor    = wsw + 3 * n + 4;
  int* bsums     = wsw + 4 * n + 4;
  int* csr       = wsw + 4 * n + 1028;
  float* hs1     = (float*)(wsw + 4 * n + 1028 + e);
  float* ms2     = hs1;  // alias: hs1 dead after k_agg1, ms2 written in k_mlp
  float* agg1    = hs1 + 64 * (size_t)n;

  const int gN = (n + TPB - 1) / TPB;
  const int gE = (e + TPB - 1) / TPB;
  const int nb = (n + 1023) / 1024;

  k_cnt_init<<<gN, TPB, 0, stream>>>(cnt, n);
  k_cnt<<<gE, TPB, 0, stream>>>(dst, cnt, e);
  k_dis<<<gN, TPB, 0, stream>>>(cnt, dis, n);
  k_scanA<<<nb, TPB, 0, stream>>>(cnt, bsums, n);
  k_scanB<<<1, 1, 0, stream>>>(bsums, nb, rowstart, n);
  k_scanC<<<nb, TPB, 0, stream>>>(cnt, bsums, rowstart, cursor, n);
  k_fill<<<gE, TPB, 0, stream>>>(src, dst, rowstart, cursor, csr, e);
  k_lin1<<<1024, TPB, 0, stream>>>(x, W1, dis, hs1, n);
  {
    int grid = (int)(((long long)n * 64 + TPB - 1) / TPB);
    k_agg1<<<grid, TPB, 0, stream>>>(rowstart, csr, hs1, dis, b1, agg1, n);
  }
  k_mlp<<<512, TPB, 0, stream>>>(agg1, Wl1, bl1, Wl2, bl2, W2, dis, ms2, n);
  {
    int grid = (int)(((long long)n * 32 + TPB - 1) / TPB);
    k_agg2<<<grid, TPB, 0, stream>>>(rowstart, csr, ms2, dis, b2, out, n);
  }
}

// Round 5
// 727.668 us; speedup vs baseline: 1.3575x; 1.0520x over previous
//
#include <hip/hip_runtime.h>

// GCN via device-built CSR (dst-indexed), gather aggregation — no float atomics.
// MLP/linear layers: lane=node, weights via wave-uniform scalar loads (s_load),
// accumulators in VGPRs, LDS only as a per-lane transpose scratch.
//
// Workspace layout (4-byte words):
//   dis      [0, n)
//   cnt      [n, 2n)          in-degree (excl self-loop), int
//   rowstart [2n, 3n+4)       exclusive scan, int (n+1 used)
//   cursor   [3n+4, 4n+4)     fill cursors, int
//   bsums    [4n+4, 4n+1028)  scan block sums, int
//   csr      [4n+1028, +e)    src indices grouped by dst
//   hs1      [.., +64n)       layer-1 messages (x@W1)*dis   (reused as ms2 later)
//   agg1     [.., +64n)       aggregated layer-1 activations

static constexpr int TPB = 256;

// ---------- degree / normalization ----------
__global__ __launch_bounds__(TPB) void k_cnt_init(int* __restrict__ cnt, int n) {
  int i = blockIdx.x * TPB + threadIdx.x;
  if (i < n) cnt[i] = 0;
}

__global__ __launch_bounds__(TPB) void k_cnt(const int* __restrict__ dst,
                                             int* __restrict__ cnt, int e) {
  int i = blockIdx.x * TPB + threadIdx.x;
  if (i < e) atomicAdd(&cnt[dst[i]], 1);
}

__global__ __launch_bounds__(TPB) void k_dis(const int* __restrict__ cnt,
                                             float* __restrict__ dis, int n) {
  int i = blockIdx.x * TPB + threadIdx.x;
  if (i < n) dis[i] = rsqrtf((float)(cnt[i] + 1));  // +1 = self-loop
}

// ---------- exclusive scan (1024 elems/block) ----------
__global__ __launch_bounds__(TPB) void k_scanA(const int* __restrict__ cnt,
                                               int* __restrict__ bsums, int n) {
  int base = blockIdx.x * 1024 + threadIdx.x * 4;
  int s = 0;
#pragma unroll
  for (int q = 0; q < 4; ++q) if (base + q < n) s += cnt[base + q];
  int lane = threadIdx.x & 63, wv = threadIdx.x >> 6;
#pragma unroll
  for (int off = 32; off; off >>= 1) s += __shfl_down(s, off);
  __shared__ int ls[4];
  if (lane == 0) ls[wv] = s;
  __syncthreads();
  if (threadIdx.x == 0) bsums[blockIdx.x] = ls[0] + ls[1] + ls[2] + ls[3];
}

__global__ void k_scanB(int* __restrict__ bsums, int nb,
                        int* __restrict__ rowstart, int n) {
  int acc = 0;
  for (int i = 0; i < nb; ++i) { int v = bsums[i]; bsums[i] = acc; acc += v; }
  rowstart[n] = acc;
}

__global__ __launch_bounds__(TPB) void k_scanC(const int* __restrict__ cnt,
                                               const int* __restrict__ bsums,
                                               int* __restrict__ rowstart,
                                               int* __restrict__ cursor, int n) {
  int base = blockIdx.x * 1024 + threadIdx.x * 4;
  int v[4] = {0, 0, 0, 0};
#pragma unroll
  for (int q = 0; q < 4; ++q) if (base + q < n) v[q] = cnt[base + q];
  int mysum = v[0] + v[1] + v[2] + v[3];
  int s = mysum;
  int lane = threadIdx.x & 63, wv = threadIdx.x >> 6;
#pragma unroll
  for (int off = 1; off < 64; off <<= 1) {
    int t = __shfl_up(s, off);
    if (lane >= off) s += t;
  }
  __shared__ int ls[4];
  if (lane == 63) ls[wv] = s;
  __syncthreads();
  int woff = 0;
  for (int w2 = 0; w2 < wv; ++w2) woff += ls[w2];
  int ex = bsums[blockIdx.x] + woff + (s - mysum);
#pragma unroll
  for (int q = 0; q < 4; ++q) {
    if (base + q < n) { rowstart[base + q] = ex; cursor[base + q] = 0; }
    ex += v[q];
  }
}

__global__ __launch_bounds__(TPB) void k_fill(const int* __restrict__ src,
                                              const int* __restrict__ dst,
                                              const int* __restrict__ rowstart,
                                              int* __restrict__ cursor,
                                              int* __restrict__ csr, int e) {
  int i = blockIdx.x * TPB + threadIdx.x;
  if (i >= e) return;
  int d = dst[i];
  int pos = rowstart[d] + atomicAdd(&cursor[d], 1);
  csr[pos] = src[i];
}

// ---------- layer 1 linear: hs1 = (x @ W1) * dis ----------
// lane = node; W1 rows read at wave-uniform addresses (scalar loads).
__global__ __launch_bounds__(64) void k_lin1(
    const float* __restrict__ x, const float* __restrict__ W1,
    const float* __restrict__ dis, float* __restrict__ hs1, int n) {
  const int lane = threadIdx.x;
  const int node = blockIdx.x * 64 + lane;
  const int nc = node < n ? node : n - 1;  // clamp for loads

  float acc[64];
#pragma unroll
  for (int j = 0; j < 64; ++j) acc[j] = 0.f;

  float4 xv = *(const float4*)&x[nc * 128];
#pragma unroll 1
  for (int kk = 0; kk < 32; ++kk) {
    float4 xn = *(const float4*)&x[nc * 128 + (((kk + 1) & 31) * 4)];
#pragma unroll
    for (int q = 0; q < 4; ++q) {
      const float xs = q == 0 ? xv.x : q == 1 ? xv.y : q == 2 ? xv.z : xv.w;
      const int k = kk * 4 + q;
#pragma unroll
      for (int j = 0; j < 64; ++j)
        acc[j] = fmaf(xs, W1[k * 64 + j], acc[j]);
    }
    xv = xn;
  }

  if (node < n) {
    const float d = dis[nc];
#pragma unroll
    for (int jj = 0; jj < 16; ++jj) {
      float4 o;
      o.x = acc[jj * 4 + 0] * d;
      o.y = acc[jj * 4 + 1] * d;
      o.z = acc[jj * 4 + 2] * d;
      o.w = acc[jj * 4 + 3] * d;
      *(float4*)&hs1[node * 64 + jj * 4] = o;
    }
  }
}

// ---------- layer-1 aggregation: one wave per node, 64 feats ----------
__global__ __launch_bounds__(TPB) void k_agg1(
    const int* __restrict__ rowstart, const int* __restrict__ csr,
    const float* __restrict__ hs1, const float* __restrict__ dis,
    const float* __restrict__ b1, float* __restrict__ agg1, int n) {
  int node = (blockIdx.x * TPB + threadIdx.x) >> 6;
  int lane = threadIdx.x & 63;
  if (node >= n) return;
  int beg = rowstart[node], end = rowstart[node + 1];
  float acc = hs1[node * 64 + lane];  // self-loop term
  for (int base = beg; base < end; base += 64) {
    int cntc = min(64, end - base);
    int sidx = (base + lane < end) ? csr[base + lane] : 0;
    for (int k = 0; k < cntc; ++k) {
      int s = __builtin_amdgcn_readlane(sidx, k);
      acc += hs1[s * 64 + lane];
    }
  }
  agg1[node * 64 + lane] = fmaf(acc, dis[node], b1[lane]);
}

// ---------- fused MLP + layer-2 linear ----------
// lane = node. t1/t2 transposed through LDS (per-lane column, conflict-free)
// so the next layer can index them with a rolled (runtime) loop variable.
__global__ __launch_bounds__(64) void k_mlp(
    const float* __restrict__ agg1,
    const float* __restrict__ Wl1, const float* __restrict__ bl1,
    const float* __restrict__ Wl2, const float* __restrict__ bl2,
    const float* __restrict__ W2, const float* __restrict__ dis,
    float* __restrict__ ms2, int n) {
  __shared__ float tT[128 * 64];  // 32 KB scratch: t1T, then t2T overlays
  const int lane = threadIdx.x;
  const int node = blockIdx.x * 64 + lane;
  const int nc = node < n ? node : n - 1;

  // ---- t1 = relu(h @ Wl1 + bl1), h = relu(agg1 row) ----
  float t1[128];
#pragma unroll
  for (int j = 0; j < 128; ++j) t1[j] = bl1[j];

  float h = fmaxf(agg1[nc * 64 + 0], 0.f);
#pragma unroll 1
  for (int k = 0; k < 64; ++k) {
    float hn = fmaxf(agg1[nc * 64 + ((k + 1) & 63)], 0.f);
#pragma unroll
    for (int j = 0; j < 128; ++j)
      t1[j] = fmaf(h, Wl1[k * 128 + j], t1[j]);
    h = hn;
  }
#pragma unroll
  for (int j = 0; j < 128; ++j) tT[j * 64 + lane] = fmaxf(t1[j], 0.f);

  // ---- t2 = relu(t1 @ Wl2 + bl2) ----
  float t2[64];
#pragma unroll
  for (int m = 0; m < 64; ++m) t2[m] = bl2[m];
#pragma unroll 1
  for (int j = 0; j < 128; ++j) {
    float tj = tT[j * 64 + lane];
#pragma unroll
    for (int m = 0; m < 64; ++m)
      t2[m] = fmaf(tj, Wl2[j * 64 + m], t2[m]);
  }
#pragma unroll
  for (int m = 0; m < 64; ++m) tT[m * 64 + lane] = fmaxf(t2[m], 0.f);

  // ---- m2 = t2 @ W2 ; ms2 = m2 * dis ----
  float mo[32];
#pragma unroll
  for (int o = 0; o < 32; ++o) mo[o] = 0.f;
#pragma unroll 1
  for (int m = 0; m < 64; ++m) {
    float tm = tT[m * 64 + lane];
#pragma unroll
    for (int o = 0; o < 32; ++o)
      mo[o] = fmaf(tm, W2[m * 32 + o], mo[o]);
  }

  if (node < n) {
    const float d = dis[nc];
#pragma unroll
    for (int oo = 0; oo < 8; ++oo) {
      float4 v;
      v.x = mo[oo * 4 + 0] * d;
      v.y = mo[oo * 4 + 1] * d;
      v.z = mo[oo * 4 + 2] * d;
      v.w = mo[oo * 4 + 3] * d;
      *(float4*)&ms2[node * 32 + oo * 4] = v;
    }
  }
}

// ---------- layer-2 aggregation: half-wave per node, 32 feats ----------
__global__ __launch_bounds__(TPB) void k_agg2(
    const int* __restrict__ rowstart, const int* __restrict__ csr,
    const float* __restrict__ ms2, const float* __restrict__ dis,
    const float* __restrict__ b2, float* __restrict__ out, int n) {
  int t = blockIdx.x * TPB + threadIdx.x;
  int node = t >> 5;
  int j = t & 31;
  if (node >= n) return;
  int beg = rowstart[node], end = rowstart[node + 1];
  float acc = ms2[node * 32 + j];  // self-loop term
  for (int k = beg; k < end; ++k) {
    int s = csr[k];
    acc += ms2[s * 32 + j];
  }
  out[node * 32 + j] = fmaf(acc, dis[node], b2[j]);
}

extern "C" void kernel_launch(void* const* d_in, const int* in_sizes, int n_in,
                              void* d_out, int out_size, void* d_ws, size_t ws_size,
                              hipStream_t stream) {
  const float* x   = (const float*)d_in[0];
  const int* ei    = (const int*)d_in[1];
  const float* W1  = (const float*)d_in[2];
  const float* b1  = (const float*)d_in[3];
  const float* Wl1 = (const float*)d_in[4];
  const float* bl1 = (const float*)d_in[5];
  const float* Wl2 = (const float*)d_in[6];
  const float* bl2 = (const float*)d_in[7];
  const float* W2  = (const float*)d_in[8];
  const float* b2  = (const float*)d_in[9];
  float* out = (float*)d_out;

  const int n = in_sizes[0] / 128;
  const int e = in_sizes[1] / 2;
  const int* src = ei;
  const int* dst = ei + e;

  int* wsw = (int*)d_ws;
  float* dis     = (float*)wsw;
  int* cnt       = wsw + n;
  int* rowstart  = wsw + 2 * n;
  int* cursor    = wsw + 3 * n + 4;
  int* bsums     = wsw + 4 * n + 4;
  int* csr       = wsw + 4 * n + 1028;
  float* hs1     = (float*)(wsw + 4 * n + 1028 + e);
  float* ms2     = hs1;  // alias: hs1 dead after k_agg1, ms2 written in k_mlp
  float* agg1    = hs1 + 64 * (size_t)n;

  const int gN = (n + TPB - 1) / TPB;
  const int gE = (e + TPB - 1) / TPB;
  const int nb = (n + 1023) / 1024;
  const int nwave = (n + 63) / 64;

  k_cnt_init<<<gN, TPB, 0, stream>>>(cnt, n);
  k_cnt<<<gE, TPB, 0, stream>>>(dst, cnt, e);
  k_dis<<<gN, TPB, 0, stream>>>(cnt, dis, n);
  k_scanA<<<nb, TPB, 0, stream>>>(cnt, bsums, n);
  k_scanB<<<1, 1, 0, stream>>>(bsums, nb, rowstart, n);
  k_scanC<<<nb, TPB, 0, stream>>>(cnt, bsums, rowstart, cursor, n);
  k_fill<<<gE, TPB, 0, stream>>>(src, dst, rowstart, cursor, csr, e);
  k_lin1<<<nwave, 64, 0, stream>>>(x, W1, dis, hs1, n);
  {
    int grid = (int)(((long long)n * 64 + TPB - 1) / TPB);
    k_agg1<<<grid, TPB, 0, stream>>>(rowstart, csr, hs1, dis, b1, agg1, n);
  }
  k_mlp<<<nwave, 64, 0, stream>>>(agg1, Wl1, bl1, Wl2, bl2, W2, dis, ms2, n);
  {
    int grid = (int)(((long long)n * 32 + TPB - 1) / TPB);
    k_agg2<<<grid, TPB, 0, stream>>>(rowstart, csr, ms2, dis, b2, out, n);
  }
}

// Round 6
// 623.227 us; speedup vs baseline: 1.5850x; 1.1676x over previous
//
#include <hip/hip_runtime.h>

// GCN via device-built CSR (dst-indexed), gather aggregation — no float atomics.
// MLP/linear layers: lane=node, weights via wave-uniform loads, accumulators in
// VGPRs, LDS only as a 16KB chunked transpose scratch (10 blocks/CU).
// Aggregation: multi-edge-in-flight float4 gathers + butterfly reduction.

static constexpr int TPB = 256;

// ---------- degree / normalization ----------
__global__ __launch_bounds__(TPB) void k_cnt_init(int* __restrict__ cnt, int n) {
  int i = blockIdx.x * TPB + threadIdx.x;
  if (i < n) cnt[i] = 0;
}

__global__ __launch_bounds__(TPB) void k_cnt(const int* __restrict__ dst,
                                             int* __restrict__ cnt, int e) {
  int i = blockIdx.x * TPB + threadIdx.x;
  if (i < e) atomicAdd(&cnt[dst[i]], 1);
}

__global__ __launch_bounds__(TPB) void k_dis(const int* __restrict__ cnt,
                                             float* __restrict__ dis, int n) {
  int i = blockIdx.x * TPB + threadIdx.x;
  if (i < n) dis[i] = rsqrtf((float)(cnt[i] + 1));  // +1 = self-loop
}

// ---------- exclusive scan (1024 elems/block) ----------
__global__ __launch_bounds__(TPB) void k_scanA(const int* __restrict__ cnt,
                                               int* __restrict__ bsums, int n) {
  int base = blockIdx.x * 1024 + threadIdx.x * 4;
  int s = 0;
#pragma unroll
  for (int q = 0; q < 4; ++q) if (base + q < n) s += cnt[base + q];
  int lane = threadIdx.x & 63, wv = threadIdx.x >> 6;
#pragma unroll
  for (int off = 32; off; off >>= 1) s += __shfl_down(s, off);
  __shared__ int ls[4];
  if (lane == 0) ls[wv] = s;
  __syncthreads();
  if (threadIdx.x == 0) bsums[blockIdx.x] = ls[0] + ls[1] + ls[2] + ls[3];
}

__global__ void k_scanB(int* __restrict__ bsums, int nb,
                        int* __restrict__ rowstart, int n) {
  int acc = 0;
  for (int i = 0; i < nb; ++i) { int v = bsums[i]; bsums[i] = acc; acc += v; }
  rowstart[n] = acc;
}

__global__ __launch_bounds__(TPB) void k_scanC(const int* __restrict__ cnt,
                                               const int* __restrict__ bsums,
                                               int* __restrict__ rowstart,
                                               int* __restrict__ cursor, int n) {
  int base = blockIdx.x * 1024 + threadIdx.x * 4;
  int v[4] = {0, 0, 0, 0};
#pragma unroll
  for (int q = 0; q < 4; ++q) if (base + q < n) v[q] = cnt[base + q];
  int mysum = v[0] + v[1] + v[2] + v[3];
  int s = mysum;
  int lane = threadIdx.x & 63, wv = threadIdx.x >> 6;
#pragma unroll
  for (int off = 1; off < 64; off <<= 1) {
    int t = __shfl_up(s, off);
    if (lane >= off) s += t;
  }
  __shared__ int ls[4];
  if (lane == 63) ls[wv] = s;
  __syncthreads();
  int woff = 0;
  for (int w2 = 0; w2 < wv; ++w2) woff += ls[w2];
  int ex = bsums[blockIdx.x] + woff + (s - mysum);
#pragma unroll
  for (int q = 0; q < 4; ++q) {
    if (base + q < n) { rowstart[base + q] = ex; cursor[base + q] = 0; }
    ex += v[q];
  }
}

__global__ __launch_bounds__(TPB) void k_fill(const int* __restrict__ src,
                                              const int* __restrict__ dst,
                                              const int* __restrict__ rowstart,
                                              int* __restrict__ cursor,
                                              int* __restrict__ csr, int e) {
  int i = blockIdx.x * TPB + threadIdx.x;
  if (i >= e) return;
  int d = dst[i];
  int pos = rowstart[d] + atomicAdd(&cursor[d], 1);
  csr[pos] = src[i];
}

// ---------- layer 1 linear: hs1 = (x @ W1) * dis ----------
// lane = node; W1 rows read at wave-uniform addresses. 4 waves/block.
__global__ __launch_bounds__(TPB) void k_lin1(
    const float* __restrict__ x, const float* __restrict__ W1,
    const float* __restrict__ dis, float* __restrict__ hs1, int n) {
  const int node = blockIdx.x * TPB + threadIdx.x;
  const int nc = node < n ? node : n - 1;  // clamp for loads

  float acc[64];
#pragma unroll
  for (int j = 0; j < 64; ++j) acc[j] = 0.f;

  float4 xv = *(const float4*)&x[(size_t)nc * 128];
#pragma unroll 1
  for (int kk = 0; kk < 32; ++kk) {
    float4 xn = *(const float4*)&x[(size_t)nc * 128 + (((kk + 1) & 31) * 4)];
#pragma unroll
    for (int q = 0; q < 4; ++q) {
      const float xs = q == 0 ? xv.x : q == 1 ? xv.y : q == 2 ? xv.z : xv.w;
      const int k = kk * 4 + q;
#pragma unroll
      for (int j = 0; j < 64; ++j)
        acc[j] = fmaf(xs, W1[k * 64 + j], acc[j]);
    }
    xv = xn;
  }

  if (node < n) {
    const float d = dis[nc];
#pragma unroll
    for (int jj = 0; jj < 16; ++jj) {
      float4 o;
      o.x = acc[jj * 4 + 0] * d;
      o.y = acc[jj * 4 + 1] * d;
      o.z = acc[jj * 4 + 2] * d;
      o.w = acc[jj * 4 + 3] * d;
      *(float4*)&hs1[(size_t)node * 64 + jj * 4] = o;
    }
  }
}

// ---------- layer-1 aggregation: one wave per node, 4 edges in flight ----------
// 16-lane groups: group g handles edges beg+g, beg+g+4, ...; lane gathers float4.
__global__ __launch_bounds__(TPB) void k_agg1(
    const int* __restrict__ rowstart, const int* __restrict__ csr,
    const float* __restrict__ hs1, const float* __restrict__ dis,
    const float* __restrict__ b1, float* __restrict__ agg1, int n) {
  int node = (blockIdx.x * TPB + threadIdx.x) >> 6;
  int lane = threadIdx.x & 63;
  if (node >= n) return;
  const int g = lane >> 4, sub = lane & 15;
  const int beg = rowstart[node], end = rowstart[node + 1];
  float4 acc = {0.f, 0.f, 0.f, 0.f};
  for (int p = beg + g; p < end; p += 4) {
    int s = csr[p];
    float4 v = *(const float4*)&hs1[(size_t)s * 64 + sub * 4];
    acc.x += v.x; acc.y += v.y; acc.z += v.z; acc.w += v.w;
  }
#pragma unroll
  for (int m = 16; m <= 32; m <<= 1) {
    acc.x += __shfl_xor(acc.x, m);
    acc.y += __shfl_xor(acc.y, m);
    acc.z += __shfl_xor(acc.z, m);
    acc.w += __shfl_xor(acc.w, m);
  }
  if (lane < 16) {
    float4 self = *(const float4*)&hs1[(size_t)node * 64 + sub * 4];
    float4 bb = *(const float4*)&b1[sub * 4];
    float d = dis[node];
    float4 o;
    o.x = fmaf(acc.x + self.x, d, bb.x);
    o.y = fmaf(acc.y + self.y, d, bb.y);
    o.z = fmaf(acc.z + self.z, d, bb.z);
    o.w = fmaf(acc.w + self.w, d, bb.w);
    *(float4*)&agg1[(size_t)node * 64 + sub * 4] = o;
  }
}

// ---------- fused MLP + layer-2 linear ----------
// lane = node. 16KB LDS: t1 transposed in two 64-wide chunks, then t2.
__global__ __launch_bounds__(64) void k_mlp(
    const float* __restrict__ agg1,
    const float* __restrict__ Wl1, const float* __restrict__ bl1,
    const float* __restrict__ Wl2, const float* __restrict__ bl2,
    const float* __restrict__ W2, const float* __restrict__ dis,
    float* __restrict__ ms2, int n) {
  __shared__ float tT[64 * 64];  // 16 KB chunked transpose scratch
  const int lane = threadIdx.x;
  const int node = blockIdx.x * 64 + lane;
  const int nc = node < n ? node : n - 1;

  // ---- t1 = relu(h @ Wl1 + bl1), h = relu(agg1 row) ----
  float t1[128];
#pragma unroll
  for (int j = 0; j < 128; ++j) t1[j] = bl1[j];

  float h = fmaxf(agg1[(size_t)nc * 64 + 0], 0.f);
#pragma unroll 1
  for (int k = 0; k < 64; ++k) {
    float hn = fmaxf(agg1[(size_t)nc * 64 + ((k + 1) & 63)], 0.f);
#pragma unroll
    for (int j = 0; j < 128; ++j)
      t1[j] = fmaf(h, Wl1[k * 128 + j], t1[j]);
    h = hn;
  }

  // ---- t2 = relu(t1 @ Wl2 + bl2), t1 consumed via 2 LDS chunks ----
  float t2[64];
#pragma unroll
  for (int m = 0; m < 64; ++m) t2[m] = bl2[m];

#pragma unroll 1
  for (int c = 0; c < 2; ++c) {
#pragma unroll
    for (int j2 = 0; j2 < 64; ++j2) tT[j2 * 64 + lane] = fmaxf(t1[c * 64 + j2], 0.f);
    __syncthreads();
#pragma unroll 1
    for (int j2 = 0; j2 < 64; ++j2) {
      float tj = tT[j2 * 64 + lane];
      const int j = c * 64 + j2;
#pragma unroll
      for (int m = 0; m < 64; ++m)
        t2[m] = fmaf(tj, Wl2[j * 64 + m], t2[m]);
    }
    __syncthreads();
  }

  // ---- m2 = t2 @ W2 ; ms2 = m2 * dis ----
#pragma unroll
  for (int m = 0; m < 64; ++m) tT[m * 64 + lane] = fmaxf(t2[m], 0.f);
  __syncthreads();

  float mo[32];
#pragma unroll
  for (int o = 0; o < 32; ++o) mo[o] = 0.f;
#pragma unroll 1
  for (int m = 0; m < 64; ++m) {
    float tm = tT[m * 64 + lane];
#pragma unroll
    for (int o = 0; o < 32; ++o)
      mo[o] = fmaf(tm, W2[m * 32 + o], mo[o]);
  }

  if (node < n) {
    const float d = dis[nc];
#pragma unroll
    for (int oo = 0; oo < 8; ++oo) {
      float4 v;
      v.x = mo[oo * 4 + 0] * d;
      v.y = mo[oo * 4 + 1] * d;
      v.z = mo[oo * 4 + 2] * d;
      v.w = mo[oo * 4 + 3] * d;
      *(float4*)&ms2[(size_t)node * 32 + oo * 4] = v;
    }
  }
}

// ---------- layer-2 aggregation: one wave per node, 8 edges in flight ----------
__global__ __launch_bounds__(TPB) void k_agg2(
    const int* __restrict__ rowstart, const int* __restrict__ csr,
    const float* __restrict__ ms2, const float* __restrict__ dis,
    const float* __restrict__ b2, float* __restrict__ out, int n) {
  int node = (blockIdx.x * TPB + threadIdx.x) >> 6;
  int lane = threadIdx.x & 63;
  if (node >= n) return;
  const int g = lane >> 3, sub = lane & 7;
  const int beg = rowstart[node], end = rowstart[node + 1];
  float4 acc = {0.f, 0.f, 0.f, 0.f};
  for (int p = beg + g; p < end; p += 8) {
    int s = csr[p];
    float4 v = *(const float4*)&ms2[(size_t)s * 32 + sub * 4];
    acc.x += v.x; acc.y += v.y; acc.z += v.z; acc.w += v.w;
  }
#pragma unroll
  for (int m = 8; m <= 32; m <<= 1) {
    acc.x += __shfl_xor(acc.x, m);
    acc.y += __shfl_xor(acc.y, m);
    acc.z += __shfl_xor(acc.z, m);
    acc.w += __shfl_xor(acc.w, m);
  }
  if (lane < 8) {
    float4 self = *(const float4*)&ms2[(size_t)node * 32 + sub * 4];
    float4 bb = *(const float4*)&b2[sub * 4];
    float d = dis[node];
    float4 o;
    o.x = fmaf(acc.x + self.x, d, bb.x);
    o.y = fmaf(acc.y + self.y, d, bb.y);
    o.z = fmaf(acc.z + self.z, d, bb.z);
    o.w = fmaf(acc.w + self.w, d, bb.w);
    *(float4*)&out[(size_t)node * 32 + sub * 4] = o;
  }
}

extern "C" void kernel_launch(void* const* d_in, const int* in_sizes, int n_in,
                              void* d_out, int out_size, void* d_ws, size_t ws_size,
                              hipStream_t stream) {
  const float* x   = (const float*)d_in[0];
  const int* ei    = (const int*)d_in[1];
  const float* W1  = (const float*)d_in[2];
  const float* b1  = (const float*)d_in[3];
  const float* Wl1 = (const float*)d_in[4];
  const float* bl1 = (const float*)d_in[5];
  const float* Wl2 = (const float*)d_in[6];
  const float* bl2 = (const float*)d_in[7];
  const float* W2  = (const float*)d_in[8];
  const float* b2  = (const float*)d_in[9];
  float* out = (float*)d_out;

  const int n = in_sizes[0] / 128;
  const int e = in_sizes[1] / 2;
  const int* src = ei;
  const int* dst = ei + e;

  int* wsw = (int*)d_ws;
  float* dis     = (float*)wsw;
  int* cnt       = wsw + n;
  int* rowstart  = wsw + 2 * n;
  int* cursor    = wsw + 3 * n + 4;
  int* bsums     = wsw + 4 * n + 4;
  int* csr       = wsw + 4 * n + 1028;
  float* hs1     = (float*)(wsw + 4 * n + 1028 + e);
  float* ms2     = hs1;  // alias: hs1 dead after k_agg1, ms2 written in k_mlp
  float* agg1    = hs1 + 64 * (size_t)n;

  const int gN = (n + TPB - 1) / TPB;
  const int gE = (e + TPB - 1) / TPB;
  const int nb = (n + 1023) / 1024;
  const int nwave = (n + 63) / 64;
  const int gAgg = (int)(((long long)n * 64 + TPB - 1) / TPB);

  k_cnt_init<<<gN, TPB, 0, stream>>>(cnt, n);
  k_cnt<<<gE, TPB, 0, stream>>>(dst, cnt, e);
  k_dis<<<gN, TPB, 0, stream>>>(cnt, dis, n);
  k_scanA<<<nb, TPB, 0, stream>>>(cnt, bsums, n);
  k_scanB<<<1, 1, 0, stream>>>(bsums, nb, rowstart, n);
  k_scanC<<<nb, TPB, 0, stream>>>(cnt, bsums, rowstart, cursor, n);
  k_fill<<<gE, TPB, 0, stream>>>(src, dst, rowstart, cursor, csr, e);
  k_lin1<<<(n + TPB - 1) / TPB, TPB, 0, stream>>>(x, W1, dis, hs1, n);
  k_agg1<<<gAgg, TPB, 0, stream>>>(rowstart, csr, hs1, dis, b1, agg1, n);
  k_mlp<<<nwave, 64, 0, stream>>>(agg1, Wl1, bl1, Wl2, bl2, W2, dis, ms2, n);
  k_agg2<<<gAgg, TPB, 0, stream>>>(rowstart, csr, ms2, dis, b2, out, n);
}

// Round 10
// 606.902 us; speedup vs baseline: 1.6276x; 1.0269x over previous
//
#include <hip/hip_runtime.h>

// GCN via device-built CSR (dst-indexed), gather aggregation — no float atomics.
// k_mlp: lane=node, hand-interchanged loops, NO register-array runtime indexing,
// no LDS, weights via contiguous wave-uniform scalar loads (Wl1 pre-transposed).

static constexpr int TPB = 256;

// ---------- degree / normalization ----------
__global__ __launch_bounds__(TPB) void k_cnt_init(int* __restrict__ cnt, int n) {
  int i = blockIdx.x * TPB + threadIdx.x;
  if (i < n) cnt[i] = 0;
}

__global__ __launch_bounds__(TPB) void k_cnt(const int* __restrict__ dst,
                                             int* __restrict__ cnt, int e) {
  int i = blockIdx.x * TPB + threadIdx.x;
  if (i < e) atomicAdd(&cnt[dst[i]], 1);
}

__global__ __launch_bounds__(TPB) void k_dis(const int* __restrict__ cnt,
                                             float* __restrict__ dis, int n) {
  int i = blockIdx.x * TPB + threadIdx.x;
  if (i < n) dis[i] = rsqrtf((float)(cnt[i] + 1));  // +1 = self-loop
}

// ---------- exclusive scan (1024 elems/block) ----------
__global__ __launch_bounds__(TPB) void k_scanA(const int* __restrict__ cnt,
                                               int* __restrict__ bsums, int n) {
  int base = blockIdx.x * 1024 + threadIdx.x * 4;
  int s = 0;
#pragma unroll
  for (int q = 0; q < 4; ++q) if (base + q < n) s += cnt[base + q];
  int lane = threadIdx.x & 63, wv = threadIdx.x >> 6;
#pragma unroll
  for (int off = 32; off; off >>= 1) s += __shfl_down(s, off);
  __shared__ int ls[4];
  if (lane == 0) ls[wv] = s;
  __syncthreads();
  if (threadIdx.x == 0) bsums[blockIdx.x] = ls[0] + ls[1] + ls[2] + ls[3];
}

__global__ void k_scanB(int* __restrict__ bsums, int nb,
                        int* __restrict__ rowstart, int n) {
  int acc = 0;
  for (int i = 0; i < nb; ++i) { int v = bsums[i]; bsums[i] = acc; acc += v; }
  rowstart[n] = acc;
}

__global__ __launch_bounds__(TPB) void k_scanC(const int* __restrict__ cnt,
                                               const int* __restrict__ bsums,
                                               int* __restrict__ rowstart,
                                               int* __restrict__ cursor, int n) {
  int base = blockIdx.x * 1024 + threadIdx.x * 4;
  int v[4] = {0, 0, 0, 0};
#pragma unroll
  for (int q = 0; q < 4; ++q) if (base + q < n) v[q] = cnt[base + q];
  int mysum = v[0] + v[1] + v[2] + v[3];
  int s = mysum;
  int lane = threadIdx.x & 63, wv = threadIdx.x >> 6;
#pragma unroll
  for (int off = 1; off < 64; off <<= 1) {
    int t = __shfl_up(s, off);
    if (lane >= off) s += t;
  }
  __shared__ int ls[4];
  if (lane == 63) ls[wv] = s;
  __syncthreads();
  int woff = 0;
  for (int w2 = 0; w2 < wv; ++w2) woff += ls[w2];
  int ex = bsums[blockIdx.x] + woff + (s - mysum);
#pragma unroll
  for (int q = 0; q < 4; ++q) {
    if (base + q < n) { rowstart[base + q] = ex; cursor[base + q] = 0; }
    ex += v[q];
  }
}

__global__ __launch_bounds__(TPB) void k_fill(const int* __restrict__ src,
                                              const int* __restrict__ dst,
                                              const int* __restrict__ rowstart,
                                              int* __restrict__ cursor,
                                              int* __restrict__ csr, int e) {
  int i = blockIdx.x * TPB + threadIdx.x;
  if (i >= e) return;
  int d = dst[i];
  int pos = rowstart[d] + atomicAdd(&cursor[d], 1);
  csr[pos] = src[i];
}

// ---------- Wl1 transpose: Wl1T[j][k] = Wl1[k][j]  (64x128 -> 128x64) ----------
__global__ __launch_bounds__(TPB) void k_wt(const float* __restrict__ Wl1,
                                            float* __restrict__ Wl1T) {
  int i = blockIdx.x * TPB + threadIdx.x;  // i = j*64 + k, 8192 total
  if (i < 128 * 64) {
    int j = i >> 6, k = i & 63;
    Wl1T[i] = Wl1[k * 128 + j];
  }
}

// ---------- layer 1 linear: hs1 = (x @ W1) * dis ----------
__global__ __launch_bounds__(TPB) void k_lin1(
    const float* __restrict__ x, const float* __restrict__ W1,
    const float* __restrict__ dis, float* __restrict__ hs1, int n) {
  const int node = blockIdx.x * TPB + threadIdx.x;
  const int nc = node < n ? node : n - 1;  // clamp for loads

  float acc[64];
#pragma unroll
  for (int j = 0; j < 64; ++j) acc[j] = 0.f;

  float4 xv = *(const float4*)&x[(size_t)nc * 128];
#pragma unroll 1
  for (int kk = 0; kk < 32; ++kk) {
    float4 xn = *(const float4*)&x[(size_t)nc * 128 + (((kk + 1) & 31) * 4)];
#pragma unroll
    for (int q = 0; q < 4; ++q) {
      const float xs = q == 0 ? xv.x : q == 1 ? xv.y : q == 2 ? xv.z : xv.w;
      const int k = kk * 4 + q;
#pragma unroll
      for (int j = 0; j < 64; ++j)
        acc[j] = fmaf(xs, W1[k * 64 + j], acc[j]);
    }
    xv = xn;
  }

  if (node < n) {
    const float d = dis[nc];
#pragma unroll
    for (int jj = 0; jj < 16; ++jj) {
      float4 o;
      o.x = acc[jj * 4 + 0] * d;
      o.y = acc[jj * 4 + 1] * d;
      o.z = acc[jj * 4 + 2] * d;
      o.w = acc[jj * 4 + 3] * d;
      *(float4*)&hs1[(size_t)node * 64 + jj * 4] = o;
    }
  }
}

// ---------- layer-1 aggregation: one wave per node, 4 edges in flight ----------
__global__ __launch_bounds__(TPB) void k_agg1(
    const int* __restrict__ rowstart, const int* __restrict__ csr,
    const float* __restrict__ hs1, const float* __restrict__ dis,
    const float* __restrict__ b1, float* __restrict__ agg1, int n) {
  int node = (blockIdx.x * TPB + threadIdx.x) >> 6;
  int lane = threadIdx.x & 63;
  if (node >= n) return;
  const int g = lane >> 4, sub = lane & 15;
  const int beg = rowstart[node], end = rowstart[node + 1];
  float4 acc = {0.f, 0.f, 0.f, 0.f};
  for (int p = beg + g; p < end; p += 4) {
    int s = csr[p];
    float4 v = *(const float4*)&hs1[(size_t)s * 64 + sub * 4];
    acc.x += v.x; acc.y += v.y; acc.z += v.z; acc.w += v.w;
  }
#pragma unroll
  for (int m = 16; m <= 32; m <<= 1) {
    acc.x += __shfl_xor(acc.x, m);
    acc.y += __shfl_xor(acc.y, m);
    acc.z += __shfl_xor(acc.z, m);
    acc.w += __shfl_xor(acc.w, m);
  }
  if (lane < 16) {
    float4 self = *(const float4*)&hs1[(size_t)node * 64 + sub * 4];
    float4 bb = *(const float4*)&b1[sub * 4];
    float d = dis[node];
    float4 o;
    o.x = fmaf(acc.x + self.x, d, bb.x);
    o.y = fmaf(acc.y + self.y, d, bb.y);
    o.z = fmaf(acc.z + self.z, d, bb.z);
    o.w = fmaf(acc.w + self.w, d, bb.w);
    *(float4*)&agg1[(size_t)node * 64 + sub * 4] = o;
  }
}

// ---------- fused MLP + layer-2 linear ----------
// lane = node. Hand-interchanged: t1 is a scalar per j (never an array);
// h[64] and t2[64] only ever statically indexed. No LDS, no spills.
__global__ __launch_bounds__(64) void k_mlp(
    const float* __restrict__ agg1,
    const float* __restrict__ Wl1T, const float* __restrict__ bl1,
    const float* __restrict__ Wl2, const float* __restrict__ bl2,
    const float* __restrict__ W2, const float* __restrict__ dis,
    float* __restrict__ ms2, int n) {
  const int lane = threadIdx.x;
  const int node = blockIdx.x * 64 + lane;
  const int nc = node < n ? node : n - 1;

  // h = relu(agg1 row), statically indexed
  float h[64];
#pragma unroll
  for (int i = 0; i < 16; ++i) {
    float4 v = *(const float4*)&agg1[(size_t)nc * 64 + i * 4];
    h[i * 4 + 0] = fmaxf(v.x, 0.f);
    h[i * 4 + 1] = fmaxf(v.y, 0.f);
    h[i * 4 + 2] = fmaxf(v.z, 0.f);
    h[i * 4 + 3] = fmaxf(v.w, 0.f);
  }

  float t2[64];
#pragma unroll
  for (int m = 0; m < 64; ++m) t2[m] = bl2[m];

#pragma unroll 2
  for (int j = 0; j < 128; ++j) {
    float t = bl1[j];
#pragma unroll
    for (int k = 0; k < 64; ++k)
      t = fmaf(h[k], Wl1T[j * 64 + k], t);
    t = fmaxf(t, 0.f);
#pragma unroll
    for (int m = 0; m < 64; ++m)
      t2[m] = fmaf(t, Wl2[j * 64 + m], t2[m]);
  }

  float mo[32];
#pragma unroll
  for (int o = 0; o < 32; ++o) mo[o] = 0.f;
#pragma unroll 2
  for (int m = 0; m < 64; ++m) {
    float tm = fmaxf(t2[m], 0.f);
#pragma unroll
    for (int o = 0; o < 32; ++o)
      mo[o] = fmaf(tm, W2[m * 32 + o], mo[o]);
  }

  if (node < n) {
    const float d = dis[nc];
#pragma unroll
    for (int oo = 0; oo < 8; ++oo) {
      float4 v;
      v.x = mo[oo * 4 + 0] * d;
      v.y = mo[oo * 4 + 1] * d;
      v.z = mo[oo * 4 + 2] * d;
      v.w = mo[oo * 4 + 3] * d;
      *(float4*)&ms2[(size_t)node * 32 + oo * 4] = v;
    }
  }
}

// ---------- layer-2 aggregation: one wave per node, 8 edges in flight ----------
__global__ __launch_bounds__(TPB) void k_agg2(
    const int* __restrict__ rowstart, const int* __restrict__ csr,
    const float* __restrict__ ms2, const float* __restrict__ dis,
    const float* __restrict__ b2, float* __restrict__ out, int n) {
  int node = (blockIdx.x * TPB + threadIdx.x) >> 6;
  int lane = threadIdx.x & 63;
  if (node >= n) return;
  const int g = lane >> 3, sub = lane & 7;
  const int beg = rowstart[node], end = rowstart[node + 1];
  float4 acc = {0.f, 0.f, 0.f, 0.f};
  for (int p = beg + g; p < end; p += 8) {
    int s = csr[p];
    float4 v = *(const float4*)&ms2[(size_t)s * 32 + sub * 4];
    acc.x += v.x; acc.y += v.y; acc.z += v.z; acc.w += v.w;
  }
#pragma unroll
  for (int m = 8; m <= 32; m <<= 1) {
    acc.x += __shfl_xor(acc.x, m);
    acc.y += __shfl_xor(acc.y, m);
    acc.z += __shfl_xor(acc.z, m);
    acc.w += __shfl_xor(acc.w, m);
  }
  if (lane < 8) {
    float4 self = *(const float4*)&ms2[(size_t)node * 32 + sub * 4];
    float4 bb = *(const float4*)&b2[sub * 4];
    float d = dis[node];
    float4 o;
    o.x = fmaf(acc.x + self.x, d, bb.x);
    o.y = fmaf(acc.y + self.y, d, bb.y);
    o.z = fmaf(acc.z + self.z, d, bb.z);
    o.w = fmaf(acc.w + self.w, d, bb.w);
    *(float4*)&out[(size_t)node * 32 + sub * 4] = o;
  }
}

extern "C" void kernel_launch(void* const* d_in, const int* in_sizes, int n_in,
                              void* d_out, int out_size, void* d_ws, size_t ws_size,
                              hipStream_t stream) {
  const float* x   = (const float*)d_in[0];
  const int* ei    = (const int*)d_in[1];
  const float* W1  = (const float*)d_in[2];
  const float* b1  = (const float*)d_in[3];
  const float* Wl1 = (const float*)d_in[4];
  const float* bl1 = (const float*)d_in[5];
  const float* Wl2 = (const float*)d_in[6];
  const float* bl2 = (const float*)d_in[7];
  const float* W2  = (const float*)d_in[8];
  const float* b2  = (const float*)d_in[9];
  float* out = (float*)d_out;

  const int n = in_sizes[0] / 128;
  const int e = in_sizes[1] / 2;
  const int* src = ei;
  const int* dst = ei + e;

  int* wsw = (int*)d_ws;
  float* dis     = (float*)wsw;
  int* cnt       = wsw + n;
  int* rowstart  = wsw + 2 * n;
  int* cursor    = wsw + 3 * n + 4;
  int* bsums     = wsw + 4 * n + 4;
  float* wl1t    = (float*)(wsw + 4 * n + 1028);
  int* csr       = wsw + 4 * n + 1028 + 8192;
  float* hs1     = (float*)(wsw + 4 * n + 1028 + 8192 + e);
  float* ms2     = hs1;  // alias: hs1 dead after k_agg1, ms2 written in k_mlp
  float* agg1    = hs1 + 64 * (size_t)n;

  const int gN = (n + TPB - 1) / TPB;
  const int gE = (e + TPB - 1) / TPB;
  const int nb = (n + 1023) / 1024;
  const int nwave = (n + 63) / 64;
  const int gAgg = (int)(((long long)n * 64 + TPB - 1) / TPB);

  k_cnt_init<<<gN, TPB, 0, stream>>>(cnt, n);
  k_cnt<<<gE, TPB, 0, stream>>>(dst, cnt, e);
  k_dis<<<gN, TPB, 0, stream>>>(cnt, dis, n);
  k_scanA<<<nb, TPB, 0, stream>>>(cnt, bsums, n);
  k_scanB<<<1, 1, 0, stream>>>(bsums, nb, rowstart, n);
  k_scanC<<<nb, TPB, 0, stream>>>(cnt, bsums, rowstart, cursor, n);
  k_fill<<<gE, TPB, 0, stream>>>(src, dst, rowstart, cursor, csr, e);
  k_wt<<<32, TPB, 0, stream>>>(Wl1, wl1t);
  k_lin1<<<(n + TPB - 1) / TPB, TPB, 0, stream>>>(x, W1, dis, hs1, n);
  k_agg1<<<gAgg, TPB, 0, stream>>>(rowstart, csr, hs1, dis, b1, agg1, n);
  k_mlp<<<nwave, 64, 0, stream>>>(agg1, wl1t, bl1, Wl2, bl2, W2, dis, ms2, n);
  k_agg2<<<gAgg, TPB, 0, stream>>>(rowstart, csr, ms2, dis, b2, out, n);
}

// Round 12
// 569.651 us; speedup vs baseline: 1.7341x; 1.0654x over previous
//
#include <hip/hip_runtime.h>

// GCN via device-built CSR (dst-indexed), gather aggregation — no float atomics.
// k_mlp: lane=node, hand-interchanged loops, statically-indexed register arrays,
// __launch_bounds__(64,1) to uncap the register allocator (kill spills),
// 4-way split accumulator chains to hide FMA latency.

static constexpr int TPB = 256;

// ---------- degree / normalization ----------
__global__ __launch_bounds__(TPB) void k_cnt_init(int* __restrict__ cnt, int n) {
  int i = blockIdx.x * TPB + threadIdx.x;
  if (i < n) cnt[i] = 0;
}

__global__ __launch_bounds__(TPB) void k_cnt(const int* __restrict__ dst,
                                             int* __restrict__ cnt, int e) {
  int i = blockIdx.x * TPB + threadIdx.x;
  if (i < e) atomicAdd(&cnt[dst[i]], 1);
}

__global__ __launch_bounds__(TPB) void k_dis(const int* __restrict__ cnt,
                                             float* __restrict__ dis, int n) {
  int i = blockIdx.x * TPB + threadIdx.x;
  if (i < n) dis[i] = rsqrtf((float)(cnt[i] + 1));  // +1 = self-loop
}

// ---------- exclusive scan (1024 elems/block) ----------
__global__ __launch_bounds__(TPB) void k_scanA(const int* __restrict__ cnt,
                                               int* __restrict__ bsums, int n) {
  int base = blockIdx.x * 1024 + threadIdx.x * 4;
  int s = 0;
#pragma unroll
  for (int q = 0; q < 4; ++q) if (base + q < n) s += cnt[base + q];
  int lane = threadIdx.x & 63, wv = threadIdx.x >> 6;
#pragma unroll
  for (int off = 32; off; off >>= 1) s += __shfl_down(s, off);
  __shared__ int ls[4];
  if (lane == 0) ls[wv] = s;
  __syncthreads();
  if (threadIdx.x == 0) bsums[blockIdx.x] = ls[0] + ls[1] + ls[2] + ls[3];
}

__global__ void k_scanB(int* __restrict__ bsums, int nb,
                        int* __restrict__ rowstart, int n) {
  int acc = 0;
  for (int i = 0; i < nb; ++i) { int v = bsums[i]; bsums[i] = acc; acc += v; }
  rowstart[n] = acc;
}

__global__ __launch_bounds__(TPB) void k_scanC(const int* __restrict__ cnt,
                                               const int* __restrict__ bsums,
                                               int* __restrict__ rowstart,
                                               int* __restrict__ cursor, int n) {
  int base = blockIdx.x * 1024 + threadIdx.x * 4;
  int v[4] = {0, 0, 0, 0};
#pragma unroll
  for (int q = 0; q < 4; ++q) if (base + q < n) v[q] = cnt[base + q];
  int mysum = v[0] + v[1] + v[2] + v[3];
  int s = mysum;
  int lane = threadIdx.x & 63, wv = threadIdx.x >> 6;
#pragma unroll
  for (int off = 1; off < 64; off <<= 1) {
    int t = __shfl_up(s, off);
    if (lane >= off) s += t;
  }
  __shared__ int ls[4];
  if (lane == 63) ls[wv] = s;
  __syncthreads();
  int woff = 0;
  for (int w2 = 0; w2 < wv; ++w2) woff += ls[w2];
  int ex = bsums[blockIdx.x] + woff + (s - mysum);
#pragma unroll
  for (int q = 0; q < 4; ++q) {
    if (base + q < n) { rowstart[base + q] = ex; cursor[base + q] = 0; }
    ex += v[q];
  }
}

__global__ __launch_bounds__(TPB) void k_fill(const int* __restrict__ src,
                                              const int* __restrict__ dst,
                                              const int* __restrict__ rowstart,
                                              int* __restrict__ cursor,
                                              int* __restrict__ csr, int e) {
  int i = blockIdx.x * TPB + threadIdx.x;
  if (i >= e) return;
  int d = dst[i];
  int pos = rowstart[d] + atomicAdd(&cursor[d], 1);
  csr[pos] = src[i];
}

// ---------- Wl1 transpose: Wl1T[j][k] = Wl1[k][j]  (64x128 -> 128x64) ----------
__global__ __launch_bounds__(TPB) void k_wt(const float* __restrict__ Wl1,
                                            float* __restrict__ Wl1T) {
  int i = blockIdx.x * TPB + threadIdx.x;  // i = j*64 + k, 8192 total
  if (i < 128 * 64) {
    int j = i >> 6, k = i & 63;
    Wl1T[i] = Wl1[k * 128 + j];
  }
}

// ---------- layer 1 linear: hs1 = (x @ W1) * dis ----------
__global__ __launch_bounds__(TPB, 1) void k_lin1(
    const float* __restrict__ x, const float* __restrict__ W1,
    const float* __restrict__ dis, float* __restrict__ hs1, int n) {
  const int node = blockIdx.x * TPB + threadIdx.x;
  const int nc = node < n ? node : n - 1;  // clamp for loads

  float acc[64];
#pragma unroll
  for (int j = 0; j < 64; ++j) acc[j] = 0.f;

  float4 xv = *(const float4*)&x[(size_t)nc * 128];
#pragma unroll 1
  for (int kk = 0; kk < 32; ++kk) {
    float4 xn = *(const float4*)&x[(size_t)nc * 128 + (((kk + 1) & 31) * 4)];
#pragma unroll
    for (int q = 0; q < 4; ++q) {
      const float xs = q == 0 ? xv.x : q == 1 ? xv.y : q == 2 ? xv.z : xv.w;
      const int k = kk * 4 + q;
#pragma unroll
      for (int j = 0; j < 64; ++j)
        acc[j] = fmaf(xs, W1[k * 64 + j], acc[j]);
    }
    xv = xn;
  }

  if (node < n) {
    const float d = dis[nc];
#pragma unroll
    for (int jj = 0; jj < 16; ++jj) {
      float4 o;
      o.x = acc[jj * 4 + 0] * d;
      o.y = acc[jj * 4 + 1] * d;
      o.z = acc[jj * 4 + 2] * d;
      o.w = acc[jj * 4 + 3] * d;
      *(float4*)&hs1[(size_t)node * 64 + jj * 4] = o;
    }
  }
}

// ---------- layer-1 aggregation: one wave per node, 4 edges in flight ----------
__global__ __launch_bounds__(TPB) void k_agg1(
    const int* __restrict__ rowstart, const int* __restrict__ csr,
    const float* __restrict__ hs1, const float* __restrict__ dis,
    const float* __restrict__ b1, float* __restrict__ agg1, int n) {
  int node = (blockIdx.x * TPB + threadIdx.x) >> 6;
  int lane = threadIdx.x & 63;
  if (node >= n) return;
  const int g = lane >> 4, sub = lane & 15;
  const int beg = rowstart[node], end = rowstart[node + 1];
  float4 acc = {0.f, 0.f, 0.f, 0.f};
  for (int p = beg + g; p < end; p += 4) {
    int s = csr[p];
    float4 v = *(const float4*)&hs1[(size_t)s * 64 + sub * 4];
    acc.x += v.x; acc.y += v.y; acc.z += v.z; acc.w += v.w;
  }
#pragma unroll
  for (int m = 16; m <= 32; m <<= 1) {
    acc.x += __shfl_xor(acc.x, m);
    acc.y += __shfl_xor(acc.y, m);
    acc.z += __shfl_xor(acc.z, m);
    acc.w += __shfl_xor(acc.w, m);
  }
  if (lane < 16) {
    float4 self = *(const float4*)&hs1[(size_t)node * 64 + sub * 4];
    float4 bb = *(const float4*)&b1[sub * 4];
    float d = dis[node];
    float4 o;
    o.x = fmaf(acc.x + self.x, d, bb.x);
    o.y = fmaf(acc.y + self.y, d, bb.y);
    o.z = fmaf(acc.z + self.z, d, bb.z);
    o.w = fmaf(acc.w + self.w, d, bb.w);
    *(float4*)&agg1[(size_t)node * 64 + sub * 4] = o;
  }
}

// ---------- fused MLP + layer-2 linear ----------
// lane = node. t1 is a scalar per j (4 split chains); h[64]/t2[64]/mo[32]
// statically indexed. __launch_bounds__(64,1): min 1 wave/EU -> VGPR cap 512,
// allocator must NOT spill (~160 live regs).
__global__ __launch_bounds__(64, 1) void k_mlp(
    const float* __restrict__ agg1,
    const float* __restrict__ Wl1T, const float* __restrict__ bl1,
    const float* __restrict__ Wl2, const float* __restrict__ bl2,
    const float* __restrict__ W2, const float* __restrict__ dis,
    float* __restrict__ ms2, int n) {
  const int lane = threadIdx.x;
  const int node = blockIdx.x * 64 + lane;
  const int nc = node < n ? node : n - 1;

  // h = relu(agg1 row), statically indexed
  float h[64];
#pragma unroll
  for (int i = 0; i < 16; ++i) {
    float4 v = *(const float4*)&agg1[(size_t)nc * 64 + i * 4];
    h[i * 4 + 0] = fmaxf(v.x, 0.f);
    h[i * 4 + 1] = fmaxf(v.y, 0.f);
    h[i * 4 + 2] = fmaxf(v.z, 0.f);
    h[i * 4 + 3] = fmaxf(v.w, 0.f);
  }

  float t2[64];
#pragma unroll
  for (int m = 0; m < 64; ++m) t2[m] = bl2[m];

#pragma unroll 1
  for (int j = 0; j < 128; ++j) {
    float ta = 0.f, tb = 0.f, tc = 0.f, td = 0.f;  // 4 independent chains
#pragma unroll
    for (int k = 0; k < 16; ++k) {
      ta = fmaf(h[k],      Wl1T[j * 64 + k],      ta);
      tb = fmaf(h[k + 16], Wl1T[j * 64 + k + 16], tb);
      tc = fmaf(h[k + 32], Wl1T[j * 64 + k + 32], tc);
      td = fmaf(h[k + 48], Wl1T[j * 64 + k + 48], td);
    }
    float t = fmaxf(((ta + tb) + (tc + td)) + bl1[j], 0.f);
#pragma unroll
    for (int m = 0; m < 64; ++m)
      t2[m] = fmaf(t, Wl2[j * 64 + m], t2[m]);
  }

  float mo[32];
#pragma unroll
  for (int o = 0; o < 32; ++o) mo[o] = 0.f;
#pragma unroll 2
  for (int m = 0; m < 64; ++m) {
    float tm = fmaxf(t2[m], 0.f);
#pragma unroll
    for (int o = 0; o < 32; ++o)
      mo[o] = fmaf(tm, W2[m * 32 + o], mo[o]);
  }

  if (node < n) {
    const float d = dis[nc];
#pragma unroll
    for (int oo = 0; oo < 8; ++oo) {
      float4 v;
      v.x = mo[oo * 4 + 0] * d;
      v.y = mo[oo * 4 + 1] * d;
      v.z = mo[oo * 4 + 2] * d;
      v.w = mo[oo * 4 + 3] * d;
      *(float4*)&ms2[(size_t)node * 32 + oo * 4] = v;
    }
  }
}

// ---------- layer-2 aggregation: one wave per node, 8 edges in flight ----------
__global__ __launch_bounds__(TPB) void k_agg2(
    const int* __restrict__ rowstart, const int* __restrict__ csr,
    const float* __restrict__ ms2, const float* __restrict__ dis,
    const float* __restrict__ b2, float* __restrict__ out, int n) {
  int node = (blockIdx.x * TPB + threadIdx.x) >> 6;
  int lane = threadIdx.x & 63;
  if (node >= n) return;
  const int g = lane >> 3, sub = lane & 7;
  const int beg = rowstart[node], end = rowstart[node + 1];
  float4 acc = {0.f, 0.f, 0.f, 0.f};
  for (int p = beg + g; p < end; p += 8) {
    int s = csr[p];
    float4 v = *(const float4*)&ms2[(size_t)s * 32 + sub * 4];
    acc.x += v.x; acc.y += v.y; acc.z += v.z; acc.w += v.w;
  }
#pragma unroll
  for (int m = 8; m <= 32; m <<= 1) {
    acc.x += __shfl_xor(acc.x, m);
    acc.y += __shfl_xor(acc.y, m);
    acc.z += __shfl_xor(acc.z, m);
    acc.w += __shfl_xor(acc.w, m);
  }
  if (lane < 8) {
    float4 self = *(const float4*)&ms2[(size_t)node * 32 + sub * 4];
    float4 bb = *(const float4*)&b2[sub * 4];
    float d = dis[node];
    float4 o;
    o.x = fmaf(acc.x + self.x, d, bb.x);
    o.y = fmaf(acc.y + self.y, d, bb.y);
    o.z = fmaf(acc.z + self.z, d, bb.z);
    o.w = fmaf(acc.w + self.w, d, bb.w);
    *(float4*)&out[(size_t)node * 32 + sub * 4] = o;
  }
}

extern "C" void kernel_launch(void* const* d_in, const int* in_sizes, int n_in,
                              void* d_out, int out_size, void* d_ws, size_t ws_size,
                              hipStream_t stream) {
  const float* x   = (const float*)d_in[0];
  const int* ei    = (const int*)d_in[1];
  const float* W1  = (const float*)d_in[2];
  const float* b1  = (const float*)d_in[3];
  const float* Wl1 = (const float*)d_in[4];
  const float* bl1 = (const float*)d_in[5];
  const float* Wl2 = (const float*)d_in[6];
  const float* bl2 = (const float*)d_in[7];
  const float* W2  = (const float*)d_in[8];
  const float* b2  = (const float*)d_in[9];
  float* out = (float*)d_out;

  const int n = in_sizes[0] / 128;
  const int e = in_sizes[1] / 2;
  const int* src = ei;
  const int* dst = ei + e;

  int* wsw = (int*)d_ws;
  float* dis     = (float*)wsw;
  int* cnt       = wsw + n;
  int* rowstart  = wsw + 2 * n;
  int* cursor    = wsw + 3 * n + 4;
  int* bsums     = wsw + 4 * n + 4;
  float* wl1t    = (float*)(wsw + 4 * n + 1028);
  int* csr       = wsw + 4 * n + 1028 + 8192;
  float* hs1     = (float*)(wsw + 4 * n + 1028 + 8192 + e);
  float* ms2     = hs1;  // alias: hs1 dead after k_agg1, ms2 written in k_mlp
  float* agg1    = hs1 + 64 * (size_t)n;

  const int gN = (n + TPB - 1) / TPB;
  const int gE = (e + TPB - 1) / TPB;
  const int nb = (n + 1023) / 1024;
  const int nwave = (n + 63) / 64;
  const int gAgg = (int)(((long long)n * 64 + TPB - 1) / TPB);

  k_cnt_init<<<gN, TPB, 0, stream>>>(cnt, n);
  k_cnt<<<gE, TPB, 0, stream>>>(dst, cnt, e);
  k_dis<<<gN, TPB, 0, stream>>>(cnt, dis, n);
  k_scanA<<<nb, TPB, 0, stream>>>(cnt, bsums, n);
  k_scanB<<<1, 1, 0, stream>>>(bsums, nb, rowstart, n);
  k_scanC<<<nb, TPB, 0, stream>>>(cnt, bsums, rowstart, cursor, n);
  k_fill<<<gE, TPB, 0, stream>>>(src, dst, rowstart, cursor, csr, e);
  k_wt<<<32, TPB, 0, stream>>>(Wl1, wl1t);
  k_lin1<<<(n + TPB - 1) / TPB, TPB, 0, stream>>>(x, W1, dis, hs1, n);
  k_agg1<<<gAgg, TPB, 0, stream>>>(rowstart, csr, hs1, dis, b1, agg1, n);
  k_mlp<<<nwave, 64, 0, stream>>>(agg1, wl1t, bl1, Wl2, bl2, W2, dis, ms2, n);
  k_agg2<<<gAgg, TPB, 0, stream>>>(rowstart, csr, ms2, dis, b2, out, n);
}